// Round 3
// baseline (335.410 us; speedup 1.0000x reference)
//
#include <hip/hip_runtime.h>
#include <hip/hip_bf16.h>

#define N_NODES 4096
#define DIMC    256   // H*D, also K of both layer GEMMs
#define NHEADS  4
#define LOG2E   1.44269504f

typedef __attribute__((ext_vector_type(8))) short  short8;
typedef __attribute__((ext_vector_type(4))) short  short4v;
typedef __attribute__((ext_vector_type(4))) float  float4v;

union S8U { short8 v; unsigned int u[4]; };

#if __has_builtin(__builtin_amdgcn_exp2f)
#define EXP2(x) __builtin_amdgcn_exp2f(x)
#else
#define EXP2(x) exp2f(x)
#endif

__device__ inline unsigned short bf16_bits(__hip_bfloat16 b) {
  union { __hip_bfloat16 b; unsigned short u; } cv; cv.b = b; return cv.u;
}

// ---------------- adjacency -> bitmask (1 bit per edge) ----------------
__global__ __launch_bounds__(256) void pack_adj_kernel(
    const int* __restrict__ adj, unsigned long long* __restrict__ bits)
{
  int wid  = blockIdx.x * 4 + (threadIdx.x >> 6);
  int lane = threadIdx.x & 63;
  int row  = wid >> 6;
  int w64  = wid & 63;
  int v = adj[(size_t)row * N_NODES + w64 * 64 + lane];
  unsigned long long m = __ballot(v > 0);
  if (lane == 0) bits[row * 64 + w64] = m;
}

// ------------- fp32 -> split bf16 (hi + residual lo), elementwise --------
__global__ __launch_bounds__(256) void split_kernel(
    const float* __restrict__ in, __hip_bfloat16* __restrict__ hi,
    __hip_bfloat16* __restrict__ lo, int n)
{
  int i = blockIdx.x * 256 + threadIdx.x;
  if (i < n) {
    float v = in[i];
    __hip_bfloat16 h = __float2bfloat16(v);
    hi[i] = h;
    lo[i] = __float2bfloat16(v - __bfloat162float(h));
  }
}

// ------- fp32 transpose + split: in[B][R][C] -> outhi(/lo)[B][C][R] ------
// grid (R/32, C/32, B), block 256. outlo may be null (hi only).
__global__ __launch_bounds__(256) void transpose_split_kernel(
    const float* __restrict__ in, __hip_bfloat16* __restrict__ outhi,
    __hip_bfloat16* __restrict__ outlo, int R, int C)
{
  __shared__ float tile[32][33];
  int t = threadIdx.x;
  int r0 = blockIdx.x * 32, c0 = blockIdx.y * 32;
  size_t base = (size_t)blockIdx.z * R * C;
  int tr = t >> 3, tc = (t & 7) * 4;
  const float* ip = in + base;
  float4v v = *reinterpret_cast<const float4v*>(ip + (size_t)(r0 + tr) * C + c0 + tc);
#pragma unroll
  for (int k = 0; k < 4; ++k) tile[tr][tc + k] = v[k];
  __syncthreads();
  short4v oh, ol;
#pragma unroll
  for (int k = 0; k < 4; ++k) {
    float f = tile[tc + k][tr];
    __hip_bfloat16 hb = __float2bfloat16(f);
    __hip_bfloat16 lb = __float2bfloat16(f - __bfloat162float(hb));
    oh[k] = (short)bf16_bits(hb);
    ol[k] = (short)bf16_bits(lb);
  }
  size_t oidx = base + (size_t)(c0 + tr) * R + r0 + tc;
  *reinterpret_cast<short4v*>(reinterpret_cast<unsigned short*>(outhi) + oidx) = oh;
  if (outlo)
    *reinterpret_cast<short4v*>(reinterpret_cast<unsigned short*>(outlo) + oidx) = ol;
}

// ---------------- h GEMM (split-bf16, 32x32 tiles) -----------------------
// out[n][c] = sum_k X[n][k]*WT[c][k]. grid (128,8), block 256 (4 waves, each
// a 16x16 sub-tile: wave w -> rows +((w>>1)*16), cols +((w&1)*16)).
__global__ __launch_bounds__(256) void gemm_kernel(
    const __hip_bfloat16* __restrict__ Xhi, const __hip_bfloat16* __restrict__ Xlo,
    const __hip_bfloat16* __restrict__ WThi, const __hip_bfloat16* __restrict__ WTlo,
    float* __restrict__ out)
{
  int t = threadIdx.x;
  int wv = t >> 6, lane = t & 63, quad = lane >> 4, col = lane & 15;
  int r0 = blockIdx.x * 32 + (wv >> 1) * 16;
  int c0 = blockIdx.y * 32 + (wv & 1) * 16;
  float4v acc = {0, 0, 0, 0};
  const unsigned short* Xh = reinterpret_cast<const unsigned short*>(Xhi);
  const unsigned short* Xl = reinterpret_cast<const unsigned short*>(Xlo);
  const unsigned short* Wh = reinterpret_cast<const unsigned short*>(WThi);
  const unsigned short* Wl = reinterpret_cast<const unsigned short*>(WTlo);
#pragma unroll
  for (int k0 = 0; k0 < DIMC; k0 += 32) {
    size_t ao = (size_t)(r0 + col) * DIMC + k0 + quad * 8;
    size_t bo = (size_t)(c0 + col) * DIMC + k0 + quad * 8;
    short8 ah = *reinterpret_cast<const short8*>(Xh + ao);
    short8 al = *reinterpret_cast<const short8*>(Xl + ao);
    short8 bh = *reinterpret_cast<const short8*>(Wh + bo);
    short8 bl = *reinterpret_cast<const short8*>(Wl + bo);
    acc = __builtin_amdgcn_mfma_f32_16x16x32_bf16(ah, bh, acc, 0, 0, 0);
    acc = __builtin_amdgcn_mfma_f32_16x16x32_bf16(ah, bl, acc, 0, 0, 0);
    acc = __builtin_amdgcn_mfma_f32_16x16x32_bf16(al, bh, acc, 0, 0, 0);
  }
#pragma unroll
  for (int r = 0; r < 4; ++r)
    out[(size_t)(r0 + quad * 4 + r) * DIMC + c0 + col] = acc[r];
}

// ---- f1/f2 (log2-scaled) from row-major fp32 hA; fused per-head max -----
// grid 1024, block 256: wave per node. lane l covers c = l*4..l*4+3.
__global__ __launch_bounds__(256) void fvec_kernel(
    const float* __restrict__ hA, const float* __restrict__ a,
    float* __restrict__ f1L, float* __restrict__ f2L,
    unsigned int* __restrict__ fmkey)
{
  int t = threadIdx.x, wv = t >> 6, lane = t & 63;
  int n = blockIdx.x * 4 + wv;
  int h = lane >> 4, d4 = (lane & 15) * 4;
  float4v v = *reinterpret_cast<const float4v*>(hA + (size_t)n * DIMC + lane * 4);
  const float* ah = a + h * 128;
  float s1 = v[0]*ah[d4] + v[1]*ah[d4+1] + v[2]*ah[d4+2] + v[3]*ah[d4+3];
  float s2 = v[0]*ah[64+d4] + v[1]*ah[64+d4+1] + v[2]*ah[64+d4+2] + v[3]*ah[64+d4+3];
#pragma unroll
  for (int o = 8; o >= 1; o >>= 1) {
    s1 += __shfl_xor(s1, o);
    s2 += __shfl_xor(s2, o);
  }
  if ((lane & 15) == 0) {
    float s2s = s2 * LOG2E;
    f1L[h * N_NODES + n] = s1 * LOG2E;
    f2L[h * N_NODES + n] = s2s;
    unsigned int u = __float_as_uint(s2s);
    unsigned int key = (u & 0x80000000u) ? ~u : (u | 0x80000000u);
    atomicMax(fmkey + h, key);
  }
}

// ---------------- fused masked-softmax-numerator @ h  --------------------
// grid (NC, 64, 4). block 256 = 4 waves x 16 rows. J-tile = 64, ping-pong
// LDS (one barrier/iter). V = hi-only bf16. Weights in log2 domain.
__global__ __launch_bounds__(256, 4) void attn_kernel(
    const __hip_bfloat16* __restrict__ hThi,   // [256][4096], row c = h*64+d
    const float* __restrict__ f1L, const float* __restrict__ f2L,
    const unsigned int* __restrict__ fmkey,
    const unsigned long long* __restrict__ bits64, // [4096][64]
    float* __restrict__ pbuf, float* __restrict__ lbuf, int Jc)
{
  __shared__ __align__(16) unsigned short hs[2][64 * 72]; // stride 72 u16 = 144B
  int t = threadIdx.x;
  int wv = t >> 6, lane = t & 63, quad = lane >> 4, col = lane & 15;
  int ch = blockIdx.x, it = blockIdx.y, h = blockIdx.z;
  int i0 = it * 64;
  int irow = i0 + wv * 16 + col;
  int j0c = ch * Jc;
  int T = Jc >> 6;

  unsigned int key = fmkey[h];
  unsigned int mbits = (key & 0x80000000u) ? (key ^ 0x80000000u) : ~key;
  float f2m = __uint_as_float(mbits);
  float f1i = f1L[h * N_NODES + irow];
  float s0 = f1i + f2m;
  float m = fmaxf(s0, 0.2f * s0);   // lrelu monotone -> valid upper-bound shift
  float f1m = f1i - m;              // s' = f1m + fv;  lr-m = max(s', 0.2*s'+cm)
  float cm = -0.8f * m;

  const unsigned short* H =
      reinterpret_cast<const unsigned short*>(hThi) + (size_t)h * 64 * N_NODES;
  const float* f2h = f2L + h * N_NODES;
  const unsigned long long* brow = bits64 + (size_t)irow * 64;

  int srow = t >> 3, soff = t & 7;  // srow 0..31, + second chunk at srow+32
  const unsigned short* g0 = H + (size_t)srow * N_NODES + soff * 8;
  const unsigned short* g1 = H + (size_t)(srow + 32) * N_NODES + soff * 8;
  int l0 = srow * 72 + soff * 8;
  int l1 = (srow + 32) * 72 + soff * 8;

  float4v acc[4] = {{0,0,0,0},{0,0,0,0},{0,0,0,0},{0,0,0,0}};
  float4v accl = {0, 0, 0, 0};
  S8U ones;
  ones.u[0] = ones.u[1] = ones.u[2] = ones.u[3] = 0x3F803F80u; // bf16 1.0 x2

  // preload tile 0 into buffer 0
  short8 rA = *reinterpret_cast<const short8*>(g0 + j0c);
  short8 rB = *reinterpret_cast<const short8*>(g1 + j0c);
  *reinterpret_cast<short8*>(&hs[0][l0]) = rA;
  *reinterpret_cast<short8*>(&hs[0][l1]) = rB;
  __syncthreads();

  for (int ti = 0; ti < T; ++ti) {
    int p = ti & 1;
    int j0 = j0c + ti * 64;
    if (ti + 1 < T) {               // prefetch next tile (global -> regs)
      rA = *reinterpret_cast<const short8*>(g0 + j0 + 64);
      rB = *reinterpret_cast<const short8*>(g1 + j0 + 64);
    }
    unsigned long long wq = brow[j0 >> 6] >> (quad * 8);
    unsigned int wb0 = (unsigned int)wq;
    unsigned int wb1 = (unsigned int)(wq >> 32);
    const unsigned short* bufp = hs[p];
#pragma unroll
    for (int jh = 0; jh < 2; ++jh) {
      unsigned int wb = jh ? wb1 : wb0;
      const float* fp = f2h + j0 + jh * 32 + quad * 8;
      float4v fa = *reinterpret_cast<const float4v*>(fp);
      float4v fb = *reinterpret_cast<const float4v*>(fp + 4);
      float w[8];
#pragma unroll
      for (int jj = 0; jj < 8; ++jj) {
        float fv = (jj < 4) ? fa[jj] : fb[jj - 4];
        float sp = f1m + fv;
        float tb = __builtin_fmaf(0.2f, sp, cm);
        float lr = fmaxf(sp, tb);
        float e = EXP2(lr);
        w[jj] = (wb & (1u << jj)) ? e : 0.0f;
      }
      S8U afr;
#pragma unroll
      for (int k2 = 0; k2 < 4; ++k2)   // truncate-pack two fp32 -> bf16x2
        afr.u[k2] = __builtin_amdgcn_perm(__float_as_uint(w[2 * k2 + 1]),
                                          __float_as_uint(w[2 * k2]),
                                          0x07060302u);
#pragma unroll
      for (int db = 0; db < 4; ++db) {
        short8 bfr = *reinterpret_cast<const short8*>(
            bufp + (db * 16 + col) * 72 + jh * 32 + quad * 8);
        acc[db] = __builtin_amdgcn_mfma_f32_16x16x32_bf16(afr.v, bfr, acc[db], 0, 0, 0);
      }
      accl = __builtin_amdgcn_mfma_f32_16x16x32_bf16(afr.v, ones.v, accl, 0, 0, 0);
    }
    if (ti + 1 < T) {               // stage next tile into other buffer
      unsigned short* d = const_cast<unsigned short*>(hs[p ^ 1]);
      *reinterpret_cast<short8*>(&d[l0]) = rA;
      *reinterpret_cast<short8*>(&d[l1]) = rB;
    }
    __syncthreads();                // single barrier per iteration
  }

  // C/D layout: col=lane&15, row=quad*4+reg
  float* pb = pbuf + ((size_t)(ch * 4 + h) * N_NODES + i0 + wv * 16) * 64;
#pragma unroll
  for (int db = 0; db < 4; ++db)
#pragma unroll
    for (int r = 0; r < 4; ++r)
      pb[(quad * 4 + r) * 64 + db * 16 + col] = acc[db][r];
  if (col == 0) {
    float* lb = lbuf + (size_t)(ch * 4 + h) * N_NODES + i0 + wv * 16;
#pragma unroll
    for (int r = 0; r < 4; ++r) lb[quad * 4 + r] = accl[r];
  }
}

// ------- combine chunks, normalize, elu; fp32 OR split-bf16 (x4 vec) -----
// grid 1024, block 256: thread handles 4 consecutive d of one (n,h).
__global__ __launch_bounds__(256) void reduce_elu_kernel(
    const float* __restrict__ pbuf, const float* __restrict__ lbuf,
    float* __restrict__ outf, __hip_bfloat16* __restrict__ outhi,
    __hip_bfloat16* __restrict__ outlo, int NC)
{
  int idx = blockIdx.x * 256 + threadIdx.x;   // 262144 total
  int n = idx >> 6, c4 = (idx & 63) * 4;
  int h = c4 >> 6, d = c4 & 63;
  float4v s = {0, 0, 0, 0};
  float l = 0.f;
  for (int ch = 0; ch < NC; ++ch) {
    size_t b = ((size_t)(ch * 4 + h) * N_NODES + n);
    float4v pv = *reinterpret_cast<const float4v*>(pbuf + b * 64 + d);
    s += pv;
    l += lbuf[b];
  }
  float rl = 1.0f / l;
  float o[4];
#pragma unroll
  for (int r = 0; r < 4; ++r) {
    float v = s[r] * rl;
    o[r] = v > 0.f ? v : EXP2(v * LOG2E) - 1.0f;
  }
  size_t oo = (size_t)n * DIMC + c4;
  if (outf) {
    *reinterpret_cast<float4v*>(outf + oo) = {o[0], o[1], o[2], o[3]};
  } else {
    short4v oh, ol;
#pragma unroll
    for (int r = 0; r < 4; ++r) {
      __hip_bfloat16 hb = __float2bfloat16(o[r]);
      oh[r] = (short)bf16_bits(hb);
      ol[r] = (short)bf16_bits(__float2bfloat16(o[r] - __bfloat162float(hb)));
    }
    *reinterpret_cast<short4v*>(reinterpret_cast<unsigned short*>(outhi) + oo) = oh;
    *reinterpret_cast<short4v*>(reinterpret_cast<unsigned short*>(outlo) + oo) = ol;
  }
}

extern "C" void kernel_launch(void* const* d_in, const int* in_sizes, int n_in,
                              void* d_out, int out_size, void* d_ws, size_t ws_size,
                              hipStream_t stream)
{
  // inputs: t, x, adj, W1, a1, W2, a2  (fp32 except adj int32)
  const float* x   = (const float*)d_in[1];
  const int*   adj = (const int*)d_in[2];
  const float* W1  = (const float*)d_in[3];
  const float* a1  = (const float*)d_in[4];
  const float* W2  = (const float*)d_in[5];
  const float* a2  = (const float*)d_in[6];

  char* ws = (char*)d_ws;
  size_t off = 0;
  auto alloc = [&](size_t b) { size_t o = off; off = (off + b + 255) & ~255ULL; return o; };
  size_t o_bits = alloc((size_t)N_NODES * 64 * 8);          // 2 MB bitmask
  size_t o_w1h  = alloc((size_t)DIMC * DIMC * 2);
  size_t o_w1l  = alloc((size_t)DIMC * DIMC * 2);
  size_t o_w2h  = alloc((size_t)DIMC * DIMC * 2);
  size_t o_w2l  = alloc((size_t)DIMC * DIMC * 2);
  size_t o_xh   = alloc((size_t)N_NODES * DIMC * 2);
  size_t o_xl   = alloc((size_t)N_NODES * DIMC * 2);
  size_t o_hA   = alloc((size_t)N_NODES * DIMC * 4);        // h fp32 row-major
  size_t o_hTh  = alloc((size_t)N_NODES * DIMC * 2);        // h^T hi only
  size_t o_x2h  = alloc((size_t)N_NODES * DIMC * 2);
  size_t o_x2l  = alloc((size_t)N_NODES * DIMC * 2);
  size_t o_f1   = alloc((size_t)NHEADS * N_NODES * 4);
  size_t o_f2   = alloc((size_t)NHEADS * N_NODES * 4);
  size_t o_fm   = alloc(256);                               // 2 layers x 4 keys

  size_t per_chunk = (size_t)NHEADS * N_NODES * 64 * 4 + (size_t)NHEADS * N_NODES * 4 + 512;
  int NC = 8;
  while (NC > 1 && off + (size_t)NC * per_chunk > ws_size) NC >>= 1;
  size_t o_pb = alloc((size_t)NC * NHEADS * N_NODES * 64 * 4);
  size_t o_lb = alloc((size_t)NC * NHEADS * N_NODES * 4);

  unsigned long long* bits = (unsigned long long*)(ws + o_bits);
  __hip_bfloat16* w1h = (__hip_bfloat16*)(ws + o_w1h);
  __hip_bfloat16* w1l = (__hip_bfloat16*)(ws + o_w1l);
  __hip_bfloat16* w2h = (__hip_bfloat16*)(ws + o_w2h);
  __hip_bfloat16* w2l = (__hip_bfloat16*)(ws + o_w2l);
  __hip_bfloat16* xh  = (__hip_bfloat16*)(ws + o_xh);
  __hip_bfloat16* xl  = (__hip_bfloat16*)(ws + o_xl);
  float*          hA  = (float*)(ws + o_hA);
  __hip_bfloat16* hTh = (__hip_bfloat16*)(ws + o_hTh);
  __hip_bfloat16* x2h = (__hip_bfloat16*)(ws + o_x2h);
  __hip_bfloat16* x2l = (__hip_bfloat16*)(ws + o_x2l);
  float* f1p = (float*)(ws + o_f1);
  float* f2p = (float*)(ws + o_f2);
  unsigned int* fmp = (unsigned int*)(ws + o_fm);
  float* pb  = (float*)(ws + o_pb);
  float* lb  = (float*)(ws + o_lb);

  hipMemsetAsync(fmp, 0, 32, stream);  // init 8 atomicMax keys (2 layers x 4 heads)
  pack_adj_kernel<<<N_NODES * 64 / 4, 256, 0, stream>>>(adj, bits);
  transpose_split_kernel<<<dim3(8, 2, 4), 256, 0, stream>>>(W1, w1h, w1l, 256, 64);
  transpose_split_kernel<<<dim3(8, 2, 4), 256, 0, stream>>>(W2, w2h, w2l, 256, 64);
  split_kernel<<<N_NODES * DIMC / 256, 256, 0, stream>>>(x, xh, xl, N_NODES * DIMC);

  auto layer = [&](const __hip_bfloat16* xih, const __hip_bfloat16* xil,
                   const __hip_bfloat16* wth, const __hip_bfloat16* wtl,
                   const float* av, unsigned int* fmk, float* outf,
                   __hip_bfloat16* oh, __hip_bfloat16* ol) {
    gemm_kernel<<<dim3(128, 8), 256, 0, stream>>>(xih, xil, wth, wtl, hA);
    transpose_split_kernel<<<dim3(128, 8, 1), 256, 0, stream>>>(hA, hTh, nullptr,
                                                                N_NODES, DIMC);
    fvec_kernel<<<1024, 256, 0, stream>>>(hA, av, f1p, f2p, fmk);
    attn_kernel<<<dim3(NC, 64, 4), 256, 0, stream>>>(hTh, f1p, f2p, fmk, bits,
                                                     pb, lb, N_NODES / NC);
    reduce_elu_kernel<<<1024, 256, 0, stream>>>(pb, lb, outf, oh, ol, NC);
  };

  layer(xh,  xl,  w1h, w1l, a1, fmp,     nullptr,        x2h, x2l);
  layer(x2h, x2l, w2h, w2l, a2, fmp + 4, (float*)d_out,  nullptr, nullptr);
}

// Round 4
// 244.433 us; speedup vs baseline: 1.3722x; 1.3722x over previous
//
#include <hip/hip_runtime.h>
#include <hip/hip_bf16.h>

#define N_NODES 4096
#define DIMC    256   // H*D, also K of both layer GEMMs
#define NHEADS  4
#define LOG2E   1.44269504f

typedef __attribute__((ext_vector_type(8))) short  short8;
typedef __attribute__((ext_vector_type(4))) short  short4v;
typedef __attribute__((ext_vector_type(4))) float  float4v;

union S8U { short8 v; unsigned int u[4]; };

#if __has_builtin(__builtin_amdgcn_exp2f)
#define EXP2(x) __builtin_amdgcn_exp2f(x)
#else
#define EXP2(x) exp2f(x)
#endif

__device__ inline unsigned short bf16_bits(__hip_bfloat16 b) {
  union { __hip_bfloat16 b; unsigned short u; } cv; cv.b = b; return cv.u;
}

// ---------------- adjacency -> bitmask (1 bit per edge) ----------------
__global__ __launch_bounds__(256) void pack_adj_kernel(
    const int* __restrict__ adj, unsigned long long* __restrict__ bits)
{
  int wid  = blockIdx.x * 4 + (threadIdx.x >> 6);
  int lane = threadIdx.x & 63;
  int row  = wid >> 6;
  int w64  = wid & 63;
  int v = adj[(size_t)row * N_NODES + w64 * 64 + lane];
  unsigned long long m = __ballot(v > 0);
  if (lane == 0) bits[row * 64 + w64] = m;
}

// ------------- fp32 -> split bf16 (hi + residual lo), elementwise --------
__global__ __launch_bounds__(256) void split_kernel(
    const float* __restrict__ in, __hip_bfloat16* __restrict__ hi,
    __hip_bfloat16* __restrict__ lo, int n)
{
  int i = blockIdx.x * 256 + threadIdx.x;
  if (i < n) {
    float v = in[i];
    __hip_bfloat16 h = __float2bfloat16(v);
    hi[i] = h;
    lo[i] = __float2bfloat16(v - __bfloat162float(h));
  }
}

// ------- fp32 transpose + split: in[B][R][C] -> outhi(/lo)[B][C][R] ------
// grid (R/32, C/32, B), block 256. outlo may be null (hi only).
__global__ __launch_bounds__(256) void transpose_split_kernel(
    const float* __restrict__ in, __hip_bfloat16* __restrict__ outhi,
    __hip_bfloat16* __restrict__ outlo, int R, int C)
{
  __shared__ float tile[32][33];
  int t = threadIdx.x;
  int r0 = blockIdx.x * 32, c0 = blockIdx.y * 32;
  size_t base = (size_t)blockIdx.z * R * C;
  int tr = t >> 3, tc = (t & 7) * 4;
  const float* ip = in + base;
  float4v v = *reinterpret_cast<const float4v*>(ip + (size_t)(r0 + tr) * C + c0 + tc);
#pragma unroll
  for (int k = 0; k < 4; ++k) tile[tr][tc + k] = v[k];
  __syncthreads();
  short4v oh, ol;
#pragma unroll
  for (int k = 0; k < 4; ++k) {
    float f = tile[tc + k][tr];
    __hip_bfloat16 hb = __float2bfloat16(f);
    __hip_bfloat16 lb = __float2bfloat16(f - __bfloat162float(hb));
    oh[k] = (short)bf16_bits(hb);
    ol[k] = (short)bf16_bits(lb);
  }
  size_t oidx = base + (size_t)(c0 + tr) * R + r0 + tc;
  *reinterpret_cast<short4v*>(reinterpret_cast<unsigned short*>(outhi) + oidx) = oh;
  if (outlo)
    *reinterpret_cast<short4v*>(reinterpret_cast<unsigned short*>(outlo) + oidx) = ol;
}

// ---------------- h GEMM (split-bf16, 32x32 tiles) -----------------------
// out[n][c] = sum_k X[n][k]*WT[c][k]. grid (128,8), block 256 (4 waves, each
// a 16x16 sub-tile: wave w -> rows +((w>>1)*16), cols +((w&1)*16)).
__global__ __launch_bounds__(256) void gemm_kernel(
    const __hip_bfloat16* __restrict__ Xhi, const __hip_bfloat16* __restrict__ Xlo,
    const __hip_bfloat16* __restrict__ WThi, const __hip_bfloat16* __restrict__ WTlo,
    float* __restrict__ out)
{
  int t = threadIdx.x;
  int wv = t >> 6, lane = t & 63, quad = lane >> 4, col = lane & 15;
  int r0 = blockIdx.x * 32 + (wv >> 1) * 16;
  int c0 = blockIdx.y * 32 + (wv & 1) * 16;
  float4v acc = {0, 0, 0, 0};
  const unsigned short* Xh = reinterpret_cast<const unsigned short*>(Xhi);
  const unsigned short* Xl = reinterpret_cast<const unsigned short*>(Xlo);
  const unsigned short* Wh = reinterpret_cast<const unsigned short*>(WThi);
  const unsigned short* Wl = reinterpret_cast<const unsigned short*>(WTlo);
#pragma unroll
  for (int k0 = 0; k0 < DIMC; k0 += 32) {
    size_t ao = (size_t)(r0 + col) * DIMC + k0 + quad * 8;
    size_t bo = (size_t)(c0 + col) * DIMC + k0 + quad * 8;
    short8 ah = *reinterpret_cast<const short8*>(Xh + ao);
    short8 al = *reinterpret_cast<const short8*>(Xl + ao);
    short8 bh = *reinterpret_cast<const short8*>(Wh + bo);
    short8 bl = *reinterpret_cast<const short8*>(Wl + bo);
    acc = __builtin_amdgcn_mfma_f32_16x16x32_bf16(ah, bh, acc, 0, 0, 0);
    acc = __builtin_amdgcn_mfma_f32_16x16x32_bf16(ah, bl, acc, 0, 0, 0);
    acc = __builtin_amdgcn_mfma_f32_16x16x32_bf16(al, bh, acc, 0, 0, 0);
  }
#pragma unroll
  for (int r = 0; r < 4; ++r)
    out[(size_t)(r0 + quad * 4 + r) * DIMC + c0 + col] = acc[r];
}

// ---- f1/f2 (log2-scaled) from row-major fp32 hA; block-level f2 max -----
// grid 1024, block 256: wave per node. lane l covers c = l*4..l*4+3.
// NO global atomics: per-(block,head) max -> pmax[block][4].
__global__ __launch_bounds__(256) void fvec_kernel(
    const float* __restrict__ hA, const float* __restrict__ a,
    float* __restrict__ f1L, float* __restrict__ f2L,
    float* __restrict__ pmax)
{
  __shared__ float bm[4][4];  // [wave][head]
  int t = threadIdx.x, wv = t >> 6, lane = t & 63;
  int n = blockIdx.x * 4 + wv;
  int h = lane >> 4, d4 = (lane & 15) * 4;
  float4v v = *reinterpret_cast<const float4v*>(hA + (size_t)n * DIMC + lane * 4);
  const float* ah = a + h * 128;
  float s1 = v[0]*ah[d4] + v[1]*ah[d4+1] + v[2]*ah[d4+2] + v[3]*ah[d4+3];
  float s2 = v[0]*ah[64+d4] + v[1]*ah[64+d4+1] + v[2]*ah[64+d4+2] + v[3]*ah[64+d4+3];
#pragma unroll
  for (int o = 8; o >= 1; o >>= 1) {
    s1 += __shfl_xor(s1, o);
    s2 += __shfl_xor(s2, o);
  }
  float s2s = s2 * LOG2E;
  if ((lane & 15) == 0) {
    f1L[h * N_NODES + n] = s1 * LOG2E;
    f2L[h * N_NODES + n] = s2s;
    bm[wv][h] = s2s;
  }
  __syncthreads();
  if (t < 4)
    pmax[blockIdx.x * 4 + t] =
        fmaxf(fmaxf(bm[0][t], bm[1][t]), fmaxf(bm[2][t], bm[3][t]));
}

// ---------------- final per-head max over 1024 block partials -------------
__global__ __launch_bounds__(256) void fmax_final_kernel(
    const float* __restrict__ pmax, float* __restrict__ f2max)
{
  __shared__ float red[256];
  int h = blockIdx.x, t = threadIdx.x;
  float m = -1e30f;
  for (int i = t; i < 1024; i += 256) m = fmaxf(m, pmax[i * 4 + h]);
  red[t] = m;
  __syncthreads();
  for (int s = 128; s > 0; s >>= 1) {
    if (t < s) red[t] = fmaxf(red[t], red[t + s]);
    __syncthreads();
  }
  if (t == 0) f2max[h] = red[0];
}

// ---------------- fused masked-softmax-numerator @ h  --------------------
// grid (NC, 64, 4). block 256 = 4 waves x 16 rows. J-tile = 64, ping-pong
// LDS (one barrier/iter). V = hi-only bf16. Weights in log2 domain.
__global__ __launch_bounds__(256, 4) void attn_kernel(
    const __hip_bfloat16* __restrict__ hThi,   // [256][4096], row c = h*64+d
    const float* __restrict__ f1L, const float* __restrict__ f2L,
    const float* __restrict__ f2max,
    const unsigned long long* __restrict__ bits64, // [4096][64]
    float* __restrict__ pbuf, float* __restrict__ lbuf, int Jc)
{
  __shared__ __align__(16) unsigned short hs[2][64 * 72]; // stride 72 u16 = 144B
  int t = threadIdx.x;
  int wv = t >> 6, lane = t & 63, quad = lane >> 4, col = lane & 15;
  int ch = blockIdx.x, it = blockIdx.y, h = blockIdx.z;
  int i0 = it * 64;
  int irow = i0 + wv * 16 + col;
  int j0c = ch * Jc;
  int T = Jc >> 6;

  float f2m = f2max[h];
  float f1i = f1L[h * N_NODES + irow];
  float s0 = f1i + f2m;
  float m = fmaxf(s0, 0.2f * s0);   // lrelu monotone -> valid upper-bound shift
  float f1m = f1i - m;              // s' = f1m + fv;  lr-m = max(s', 0.2*s'+cm)
  float cm = -0.8f * m;

  const unsigned short* H =
      reinterpret_cast<const unsigned short*>(hThi) + (size_t)h * 64 * N_NODES;
  const float* f2h = f2L + h * N_NODES;
  const unsigned long long* brow = bits64 + (size_t)irow * 64;

  int srow = t >> 3, soff = t & 7;  // srow 0..31, + second chunk at srow+32
  const unsigned short* g0 = H + (size_t)srow * N_NODES + soff * 8;
  const unsigned short* g1 = H + (size_t)(srow + 32) * N_NODES + soff * 8;
  int l0 = srow * 72 + soff * 8;
  int l1 = (srow + 32) * 72 + soff * 8;

  float4v acc[4] = {{0,0,0,0},{0,0,0,0},{0,0,0,0},{0,0,0,0}};
  float4v accl = {0, 0, 0, 0};
  S8U ones;
  ones.u[0] = ones.u[1] = ones.u[2] = ones.u[3] = 0x3F803F80u; // bf16 1.0 x2

  // preload tile 0 into buffer 0
  short8 rA = *reinterpret_cast<const short8*>(g0 + j0c);
  short8 rB = *reinterpret_cast<const short8*>(g1 + j0c);
  *reinterpret_cast<short8*>(&hs[0][l0]) = rA;
  *reinterpret_cast<short8*>(&hs[0][l1]) = rB;
  __syncthreads();

  for (int ti = 0; ti < T; ++ti) {
    int p = ti & 1;
    int j0 = j0c + ti * 64;
    if (ti + 1 < T) {               // prefetch next tile (global -> regs)
      rA = *reinterpret_cast<const short8*>(g0 + j0 + 64);
      rB = *reinterpret_cast<const short8*>(g1 + j0 + 64);
    }
    unsigned long long wq = brow[j0 >> 6] >> (quad * 8);
    unsigned int wb0 = (unsigned int)wq;
    unsigned int wb1 = (unsigned int)(wq >> 32);
    const unsigned short* bufp = hs[p];
#pragma unroll
    for (int jh = 0; jh < 2; ++jh) {
      unsigned int wb = jh ? wb1 : wb0;
      const float* fp = f2h + j0 + jh * 32 + quad * 8;
      float4v fa = *reinterpret_cast<const float4v*>(fp);
      float4v fb = *reinterpret_cast<const float4v*>(fp + 4);
      float w[8];
#pragma unroll
      for (int jj = 0; jj < 8; ++jj) {
        float fv = (jj < 4) ? fa[jj] : fb[jj - 4];
        float sp = f1m + fv;
        float tb = __builtin_fmaf(0.2f, sp, cm);
        float lr = fmaxf(sp, tb);
        float e = EXP2(lr);
        w[jj] = (wb & (1u << jj)) ? e : 0.0f;
      }
      S8U afr;
#pragma unroll
      for (int k2 = 0; k2 < 4; ++k2)   // truncate-pack two fp32 -> bf16x2
        afr.u[k2] = __builtin_amdgcn_perm(__float_as_uint(w[2 * k2 + 1]),
                                          __float_as_uint(w[2 * k2]),
                                          0x07060302u);
#pragma unroll
      for (int db = 0; db < 4; ++db) {
        short8 bfr = *reinterpret_cast<const short8*>(
            bufp + (db * 16 + col) * 72 + jh * 32 + quad * 8);
        acc[db] = __builtin_amdgcn_mfma_f32_16x16x32_bf16(afr.v, bfr, acc[db], 0, 0, 0);
      }
      accl = __builtin_amdgcn_mfma_f32_16x16x32_bf16(afr.v, ones.v, accl, 0, 0, 0);
    }
    if (ti + 1 < T) {               // stage next tile into other buffer
      unsigned short* d = const_cast<unsigned short*>(hs[p ^ 1]);
      *reinterpret_cast<short8*>(&d[l0]) = rA;
      *reinterpret_cast<short8*>(&d[l1]) = rB;
    }
    __syncthreads();                // single barrier per iteration
  }

  // C/D layout: col=lane&15, row=quad*4+reg
  float* pb = pbuf + ((size_t)(ch * 4 + h) * N_NODES + i0 + wv * 16) * 64;
#pragma unroll
  for (int db = 0; db < 4; ++db)
#pragma unroll
    for (int r = 0; r < 4; ++r)
      pb[(quad * 4 + r) * 64 + db * 16 + col] = acc[db][r];
  if (col == 0) {
    float* lb = lbuf + (size_t)(ch * 4 + h) * N_NODES + i0 + wv * 16;
#pragma unroll
    for (int r = 0; r < 4; ++r) lb[quad * 4 + r] = accl[r];
  }
}

// ------- combine chunks, normalize, elu; fp32 OR split-bf16 (x4 vec) -----
// grid 1024, block 256: thread handles 4 consecutive d of one (n,h).
__global__ __launch_bounds__(256) void reduce_elu_kernel(
    const float* __restrict__ pbuf, const float* __restrict__ lbuf,
    float* __restrict__ outf, __hip_bfloat16* __restrict__ outhi,
    __hip_bfloat16* __restrict__ outlo, int NC)
{
  int idx = blockIdx.x * 256 + threadIdx.x;   // 262144 total
  int n = idx >> 6, c4 = (idx & 63) * 4;
  int h = c4 >> 6, d = c4 & 63;
  float4v s = {0, 0, 0, 0};
  float l = 0.f;
  for (int ch = 0; ch < NC; ++ch) {
    size_t b = ((size_t)(ch * 4 + h) * N_NODES + n);
    float4v pv = *reinterpret_cast<const float4v*>(pbuf + b * 64 + d);
    s += pv;
    l += lbuf[b];
  }
  float rl = 1.0f / l;
  float o[4];
#pragma unroll
  for (int r = 0; r < 4; ++r) {
    float v = s[r] * rl;
    o[r] = v > 0.f ? v : EXP2(v * LOG2E) - 1.0f;
  }
  size_t oo = (size_t)n * DIMC + c4;
  if (outf) {
    *reinterpret_cast<float4v*>(outf + oo) = {o[0], o[1], o[2], o[3]};
  } else {
    short4v oh, ol;
#pragma unroll
    for (int r = 0; r < 4; ++r) {
      __hip_bfloat16 hb = __float2bfloat16(o[r]);
      oh[r] = (short)bf16_bits(hb);
      ol[r] = (short)bf16_bits(__float2bfloat16(o[r] - __bfloat162float(hb)));
    }
    *reinterpret_cast<short4v*>(reinterpret_cast<unsigned short*>(outhi) + oo) = oh;
    *reinterpret_cast<short4v*>(reinterpret_cast<unsigned short*>(outlo) + oo) = ol;
  }
}

extern "C" void kernel_launch(void* const* d_in, const int* in_sizes, int n_in,
                              void* d_out, int out_size, void* d_ws, size_t ws_size,
                              hipStream_t stream)
{
  // inputs: t, x, adj, W1, a1, W2, a2  (fp32 except adj int32)
  const float* x   = (const float*)d_in[1];
  const int*   adj = (const int*)d_in[2];
  const float* W1  = (const float*)d_in[3];
  const float* a1  = (const float*)d_in[4];
  const float* W2  = (const float*)d_in[5];
  const float* a2  = (const float*)d_in[6];

  char* ws = (char*)d_ws;
  size_t off = 0;
  auto alloc = [&](size_t b) { size_t o = off; off = (off + b + 255) & ~255ULL; return o; };
  size_t o_bits = alloc((size_t)N_NODES * 64 * 8);          // 2 MB bitmask
  size_t o_w1h  = alloc((size_t)DIMC * DIMC * 2);
  size_t o_w1l  = alloc((size_t)DIMC * DIMC * 2);
  size_t o_w2h  = alloc((size_t)DIMC * DIMC * 2);
  size_t o_w2l  = alloc((size_t)DIMC * DIMC * 2);
  size_t o_xh   = alloc((size_t)N_NODES * DIMC * 2);
  size_t o_xl   = alloc((size_t)N_NODES * DIMC * 2);
  size_t o_hA   = alloc((size_t)N_NODES * DIMC * 4);        // h fp32 row-major
  size_t o_hTh  = alloc((size_t)N_NODES * DIMC * 2);        // h^T hi only
  size_t o_x2h  = alloc((size_t)N_NODES * DIMC * 2);
  size_t o_x2l  = alloc((size_t)N_NODES * DIMC * 2);
  size_t o_f1   = alloc((size_t)NHEADS * N_NODES * 4);
  size_t o_f2   = alloc((size_t)NHEADS * N_NODES * 4);
  size_t o_pm   = alloc((size_t)1024 * 4 * 4);              // per-block head maxes
  size_t o_fm   = alloc(256);                               // 2 layers x 4 floats

  size_t per_chunk = (size_t)NHEADS * N_NODES * 64 * 4 + (size_t)NHEADS * N_NODES * 4 + 512;
  int NC = 8;
  while (NC > 1 && off + (size_t)NC * per_chunk > ws_size) NC >>= 1;
  size_t o_pb = alloc((size_t)NC * NHEADS * N_NODES * 64 * 4);
  size_t o_lb = alloc((size_t)NC * NHEADS * N_NODES * 4);

  unsigned long long* bits = (unsigned long long*)(ws + o_bits);
  __hip_bfloat16* w1h = (__hip_bfloat16*)(ws + o_w1h);
  __hip_bfloat16* w1l = (__hip_bfloat16*)(ws + o_w1l);
  __hip_bfloat16* w2h = (__hip_bfloat16*)(ws + o_w2h);
  __hip_bfloat16* w2l = (__hip_bfloat16*)(ws + o_w2l);
  __hip_bfloat16* xh  = (__hip_bfloat16*)(ws + o_xh);
  __hip_bfloat16* xl  = (__hip_bfloat16*)(ws + o_xl);
  float*          hA  = (float*)(ws + o_hA);
  __hip_bfloat16* hTh = (__hip_bfloat16*)(ws + o_hTh);
  __hip_bfloat16* x2h = (__hip_bfloat16*)(ws + o_x2h);
  __hip_bfloat16* x2l = (__hip_bfloat16*)(ws + o_x2l);
  float* f1p = (float*)(ws + o_f1);
  float* f2p = (float*)(ws + o_f2);
  float* pmx = (float*)(ws + o_pm);
  float* fmp = (float*)(ws + o_fm);
  float* pb  = (float*)(ws + o_pb);
  float* lb  = (float*)(ws + o_lb);

  pack_adj_kernel<<<N_NODES * 64 / 4, 256, 0, stream>>>(adj, bits);
  transpose_split_kernel<<<dim3(8, 2, 4), 256, 0, stream>>>(W1, w1h, w1l, 256, 64);
  transpose_split_kernel<<<dim3(8, 2, 4), 256, 0, stream>>>(W2, w2h, w2l, 256, 64);
  split_kernel<<<N_NODES * DIMC / 256, 256, 0, stream>>>(x, xh, xl, N_NODES * DIMC);

  auto layer = [&](const __hip_bfloat16* xih, const __hip_bfloat16* xil,
                   const __hip_bfloat16* wth, const __hip_bfloat16* wtl,
                   const float* av, float* fmk, float* outf,
                   __hip_bfloat16* oh, __hip_bfloat16* ol) {
    gemm_kernel<<<dim3(128, 8), 256, 0, stream>>>(xih, xil, wth, wtl, hA);
    transpose_split_kernel<<<dim3(128, 8, 1), 256, 0, stream>>>(hA, hTh, nullptr,
                                                                N_NODES, DIMC);
    fvec_kernel<<<1024, 256, 0, stream>>>(hA, av, f1p, f2p, pmx);
    fmax_final_kernel<<<4, 256, 0, stream>>>(pmx, fmk);
    attn_kernel<<<dim3(NC, 64, 4), 256, 0, stream>>>(hTh, f1p, f2p, fmk, bits,
                                                     pb, lb, N_NODES / NC);
    reduce_elu_kernel<<<1024, 256, 0, stream>>>(pb, lb, outf, oh, ol, NC);
  };

  layer(xh,  xl,  w1h, w1l, a1, fmp,     nullptr,        x2h, x2l);
  layer(x2h, x2l, w2h, w2l, a2, fmp + 4, (float*)d_out,  nullptr, nullptr);
}